// Round 5
// baseline (1723.231 us; speedup 1.0000x reference)
//
#include <hip/hip_runtime.h>

typedef _Float16 f16;
typedef _Float16 f16x8 __attribute__((ext_vector_type(8)));
typedef float f32x4 __attribute__((ext_vector_type(4)));

#define DIM 256
#define HID 512

// ws element offsets (f16 units)
#define WSO_W1  0
#define WSO_W2  131072
#define WSO_WC1 262144
#define WSO_WC2 278528
#define PACK_TOTAL 279552

// LDS byte layout (dynamic smem): W1 kt4..7 frags | yst | hbuf(+h1)
#define LDS_W1   0
#define LDS_YST  131072
#define LDS_HB   139264
#define SMEM_BYTES 155648   // 152 KB -> 1 block/CU

#define MFMA(a, b, c) __builtin_amdgcn_mfma_f32_16x16x32_f16(a, b, c, 0, 0, 0)

// Pack weights into MFMA B-fragment order (16x16x32_f16):
// frag (kt,nt): lane l, elem j -> B[k = kt*32 + (l>>4)*8 + j][n = nt*16 + (l&15)]
__global__ void pack_weights(const float* __restrict__ W1, const float* __restrict__ W2,
                             const float* __restrict__ Wc1, const float* __restrict__ Wc2,
                             f16* __restrict__ ws) {
    int gid = blockIdx.x * 256 + threadIdx.x;
    if (gid >= PACK_TOTAL) return;
    if (gid < WSO_W2) {
        int g = gid;
        int j = g & 7, lane = (g >> 3) & 63, fi = g >> 9;
        int kt = fi >> 5, nt = fi & 31;                 // 8 x 32 frags
        int k = kt * 32 + ((lane >> 4) << 3) + j;
        int n = (nt << 4) + (lane & 15);
        ws[WSO_W1 + g] = (f16)W1[k * HID + n];
    } else if (gid < WSO_WC1) {
        int g = gid - WSO_W2;
        int j = g & 7, lane = (g >> 3) & 63, fi = g >> 9;
        int kt = fi >> 4, nt = fi & 15;                 // 16 x 16 frags
        int k = kt * 32 + ((lane >> 4) << 3) + j;
        int n = (nt << 4) + (lane & 15);
        ws[WSO_W2 + g] = (f16)W2[k * DIM + n];
    } else if (gid < WSO_WC2) {
        int g = gid - WSO_WC1;
        int j = g & 7, lane = (g >> 3) & 63, fi = g >> 9;
        int kt = fi >> 2, nt = fi & 3;                  // 8 x 4 frags
        int k = kt * 32 + ((lane >> 4) << 3) + j;
        int n = (nt << 4) + (lane & 15);
        ws[WSO_WC1 + g] = (f16)Wc1[k * 64 + n];
    } else {
        int g = gid - WSO_WC2;
        int j = g & 7, lane = (g >> 3) & 63, kt = g >> 9; // 2 frags
        int k = kt * 32 + ((lane >> 4) << 3) + j;
        int n = lane & 15;
        ws[WSO_WC2 + g] = (n < 10) ? (f16)Wc2[k * 10 + n] : (f16)0.0f;
    }
}

__device__ __forceinline__ float tanh_fast(float x) {
    float e = __expf(2.0f * x);
    return 1.0f - 2.0f * __builtin_amdgcn_rcpf(e + 1.0f);
}

// f(ys) = tanh(ys@W1+b1)@W2+b2 for the block's 16 rows. 8 waves.
// Wave w: m1 n-tiles 4w..4w+3 (HID), m2 n-tiles 2w,2w+1 (DIM).
// Thread slot layout: row = (lane>>4)*4+i ; col = w*32 + t*16 + (lane&15), t in 0..1
template <class FIN, class FOUT>
__device__ __forceinline__ void feval(FIN yin, FOUT kout,
        const f16* __restrict__ ws, const f16* w1lds, f16* yst, f16* hbuf,
        const f16x8 (&w1r)[4][4], const f16x8 (&w2r)[2][8],
        int lane, int w, const float b1c[4], const float b2c[2]) {
    const int cn   = lane & 15;
    const int rlo  = (lane >> 4) << 2;
    const int koff = (lane >> 4) << 3;

#define LDW2(KT, T) (*(const f16x8*)(ws + WSO_W2 + ((((KT) * 16 + 2 * w + (T)) << 9) + lane * 8)))

    // ---- write stage input, swizzled f16 [16][256] ----
    #pragma unroll
    for (int t = 0; t < 2; ++t)
        #pragma unroll
        for (int i = 0; i < 4; ++i) {
            int row = rlo + i;
            int col = w * 32 + t * 16 + cn;
            int idx = ((row << 8) + col) ^ ((row & 7) << 3);
            yst[idx] = (f16)yin(t, i);
        }
    __syncthreads();   // BARRIER_A

    // ---- issue W2 stream preloads (kt8..10) AFTER the barrier so no drain stall;
    //      consumed in m2, ~600+ cyc of m1 in between ----
    f16x8 w2s[3][2];
    #pragma unroll
    for (int st = 0; st < 3; ++st) {
        w2s[st][0] = LDW2(8 + st, 0);
        w2s[st][1] = LDW2(8 + st, 1);
    }

    // ---- m1: h = ys @ W1 ; W1 kt0-3 regs, kt4-7 LDS ----
    f32x4 acc[4];
    #pragma unroll
    for (int q = 0; q < 4; ++q) acc[q] = (f32x4){0.f, 0.f, 0.f, 0.f};
    #pragma unroll
    for (int kt = 0; kt < 8; ++kt) {
        int aidx = ((cn << 8) + kt * 32 + koff) ^ ((cn & 7) << 3);
        f16x8 af = *(const f16x8*)(yst + aidx);
        #pragma unroll
        for (int q = 0; q < 4; ++q) {
            f16x8 wf;
            if (kt < 4) wf = w1r[q][kt];
            else        wf = *(const f16x8*)(w1lds + (((kt - 4) * 32 + 4 * w + q) << 9) + lane * 8);
            acc[q] = MFMA(af, wf, acc[q]);
        }
    }
    // tanh -> swizzled hbuf [16][512]
    #pragma unroll
    for (int q = 0; q < 4; ++q) {
        int hcol = ((4 * w + q) << 4) + cn;
        #pragma unroll
        for (int i = 0; i < 4; ++i) {
            float th = tanh_fast(acc[q][i] + b1c[q]);
            int row = rlo + i;
            int idx = ((row << 9) + hcol) ^ ((row & 7) << 3);
            hbuf[idx] = (f16)th;
        }
    }
    __syncthreads();   // BARRIER_B

    // ---- m2: k = h @ W2 + b2 ; regs kt0-7, stream kt8-15 via 3-slot window ----
    f32x4 acc2[2];
    acc2[0] = (f32x4){0.f, 0.f, 0.f, 0.f};
    acc2[1] = (f32x4){0.f, 0.f, 0.f, 0.f};

#define M2STEP(KT, B0, B1) { \
        int aidx = ((cn << 9) + (KT) * 32 + koff) ^ ((cn & 7) << 3); \
        f16x8 af = *(const f16x8*)(hbuf + aidx); \
        acc2[0] = MFMA(af, B0, acc2[0]); \
        acc2[1] = MFMA(af, B1, acc2[1]); }

    // order: 8,9,10 (refill 11,12,13), 0-3, 11,12,13 (refill 14,15), 4,5, 14,15, 6,7
    #pragma unroll
    for (int st = 0; st < 3; ++st) {
        M2STEP(8 + st, w2s[st][0], w2s[st][1]);
        w2s[st][0] = LDW2(11 + st, 0);
        w2s[st][1] = LDW2(11 + st, 1);
    }
    #pragma unroll
    for (int kt = 0; kt < 4; ++kt) M2STEP(kt, w2r[0][kt], w2r[1][kt]);
    M2STEP(11, w2s[0][0], w2s[0][1]);
    w2s[0][0] = LDW2(14, 0); w2s[0][1] = LDW2(14, 1);
    M2STEP(12, w2s[1][0], w2s[1][1]);
    w2s[1][0] = LDW2(15, 0); w2s[1][1] = LDW2(15, 1);
    M2STEP(13, w2s[2][0], w2s[2][1]);
    M2STEP(4, w2r[0][4], w2r[1][4]);
    M2STEP(5, w2r[0][5], w2r[1][5]);
    M2STEP(14, w2s[0][0], w2s[0][1]);
    M2STEP(15, w2s[1][0], w2s[1][1]);
    M2STEP(6, w2r[0][6], w2r[1][6]);
    M2STEP(7, w2r[0][7], w2r[1][7]);
#undef M2STEP
#undef LDW2

    #pragma unroll
    for (int t = 0; t < 2; ++t)
        #pragma unroll
        for (int i = 0; i < 4; ++i)
            kout(t, i, acc2[t][i] + b2c[t]);
}

__launch_bounds__(512, 2)
__attribute__((amdgpu_waves_per_eu(2, 2)))
__global__ void ode_main(const float* __restrict__ x0, const float* __restrict__ tg,
                         const float* __restrict__ b1, const float* __restrict__ b2,
                         const float* __restrict__ bc1, const float* __restrict__ bc2,
                         const f16* __restrict__ ws, float* __restrict__ out) {
    extern __shared__ char smem[];
    f16* w1lds = (f16*)(smem + LDS_W1);
    f16* yst   = (f16*)(smem + LDS_YST);
    f16* hbuf  = (f16*)(smem + LDS_HB);

    const int tid  = threadIdx.x;
    const int lane = tid & 63;
    const int w    = tid >> 6;            // wave 0..7
    const int r0   = blockIdx.x * 16;
    const int cn   = lane & 15;
    const int rlo  = (lane >> 4) << 2;

    // ---- one-time: W1 kt4..7 into LDS (frag-linear, 128 KB) ----
    #pragma unroll
    for (int u = 0; u < 16; ++u) {
        int e = (u * 512 + tid) * 8;
        *(f16x8*)(w1lds + e) = *(const f16x8*)(ws + WSO_W1 + 65536 + e);
    }

    // ---- one-time: register-resident weight fragments ----
    f16x8 w1r[4][4];   // W1 kt0-3
    #pragma unroll
    for (int q = 0; q < 4; ++q)
        #pragma unroll
        for (int kt = 0; kt < 4; ++kt)
            w1r[q][kt] = *(const f16x8*)(ws + WSO_W1 + (((kt * 32 + 4 * w + q) << 9) + lane * 8));

    f16x8 w2r[2][8];   // W2 kt0-7
    #pragma unroll
    for (int t = 0; t < 2; ++t)
        #pragma unroll
        for (int kt = 0; kt < 8; ++kt)
            w2r[t][kt] = *(const f16x8*)(ws + WSO_W2 + (((kt * 16 + 2 * w + t) << 9) + lane * 8));

    float b1c[4], b2c[2];
    #pragma unroll
    for (int q = 0; q < 4; ++q) b1c[q] = b1[((4 * w + q) << 4) + cn];
    #pragma unroll
    for (int t = 0; t < 2; ++t) b2c[t] = b2[((2 * w + t) << 4) + cn];

    // state: row = r0 + rlo + i, col = w*32 + t*16 + cn
    float y[2][4];
    #pragma unroll
    for (int t = 0; t < 2; ++t)
        #pragma unroll
        for (int i = 0; i < 4; ++i)
            y[t][i] = x0[(r0 + rlo + i) * DIM + w * 32 + t * 16 + cn];

    __syncthreads();  // W1 LDS fill visible

    float k1[2][4], k2[2][4], k3[2][4], k4[2][4], k5[2][4];
    float dt = 0.f;

    for (int s = 0; s < 28; ++s) {
        if ((s & 3) == 0) { int iv = s >> 2; dt = (tg[iv + 1] - tg[iv]) * 0.25f; }

        feval([&](int t, int i) { return y[t][i]; },
              [&](int t, int i, float v) { k1[t][i] = v; },
              ws, w1lds, yst, hbuf, w1r, w2r, lane, w, b1c, b2c);
        feval([&](int t, int i) { return y[t][i] + dt * 0.2f * k1[t][i]; },
              [&](int t, int i, float v) { k2[t][i] = v; },
              ws, w1lds, yst, hbuf, w1r, w2r, lane, w, b1c, b2c);
        feval([&](int t, int i) { return y[t][i] + dt * (0.075f * k1[t][i] + 0.225f * k2[t][i]); },
              [&](int t, int i, float v) { k3[t][i] = v; },
              ws, w1lds, yst, hbuf, w1r, w2r, lane, w, b1c, b2c);
        feval([&](int t, int i) { return y[t][i] + dt * ((44.f/45.f) * k1[t][i] + (-56.f/15.f) * k2[t][i]
                                                        + (32.f/9.f) * k3[t][i]); },
              [&](int t, int i, float v) { k4[t][i] = v; },
              ws, w1lds, yst, hbuf, w1r, w2r, lane, w, b1c, b2c);
        feval([&](int t, int i) { return y[t][i] + dt * ((19372.f/6561.f) * k1[t][i] + (-25360.f/2187.f) * k2[t][i]
                                                        + (64448.f/6561.f) * k3[t][i] + (-212.f/729.f) * k4[t][i]); },
              [&](int t, int i, float v) { k5[t][i] = v; },
              ws, w1lds, yst, hbuf, w1r, w2r, lane, w, b1c, b2c);
        // stage 6: fold k6 straight into y (k6 never stored)
        feval([&](int t, int i) { return y[t][i] + dt * ((9017.f/3168.f) * k1[t][i] + (-355.f/33.f) * k2[t][i]
                                                        + (46732.f/5247.f) * k3[t][i] + (49.f/176.f) * k4[t][i]
                                                        + (-5103.f/18656.f) * k5[t][i]); },
              [&](int t, int i, float v) {
                  y[t][i] += dt * ((35.f/384.f)    * k1[t][i] + (500.f/1113.f)  * k3[t][i]
                                 + (125.f/192.f)   * k4[t][i] + (-2187.f/6784.f) * k5[t][i]
                                 + (11.f/84.f)     * v);
              },
              ws, w1lds, yst, hbuf, w1r, w2r, lane, w, b1c, b2c);
    }

    // ---------------- classifier head ----------------
    #pragma unroll
    for (int t = 0; t < 2; ++t)
        #pragma unroll
        for (int i = 0; i < 4; ++i) {
            int row = rlo + i;
            int col = w * 32 + t * 16 + cn;
            int idx = ((row << 8) + col) ^ ((row & 7) << 3);
            yst[idx] = (f16)y[t][i];
        }
    __syncthreads();

    // h1 = relu(y @ Wc1 + bc1): waves 0..3, one 16-col tile each; h1 in hbuf
    if (w < 4) {
        const int koff = (lane >> 4) << 3;
        f32x4 ha = (f32x4){0.f, 0.f, 0.f, 0.f};
        #pragma unroll
        for (int kt = 0; kt < 8; ++kt) {
            int aidx = ((cn << 8) + kt * 32 + koff) ^ ((cn & 7) << 3);
            f16x8 af = *(const f16x8*)(yst + aidx);
            f16x8 wf = *(const f16x8*)(ws + WSO_WC1 + (((kt * 4 + w) << 9) + lane * 8));
            ha = MFMA(af, wf, ha);
        }
        float bb = bc1[(w << 4) + cn];
        #pragma unroll
        for (int i = 0; i < 4; ++i) {
            float v = fmaxf(ha[i] + bb, 0.f);
            int row = rlo + i;
            int idx = ((row << 6) + (w << 4) + cn) ^ ((row & 7) << 3);
            hbuf[idx] = (f16)v;
        }
    }
    __syncthreads();

    // logits = h1 @ Wc2 + bc2 (packed cols 10..15 zero): wave 0
    if (w == 0) {
        const int koff = (lane >> 4) << 3;
        f32x4 acc = (f32x4){0.f, 0.f, 0.f, 0.f};
        #pragma unroll
        for (int kt = 0; kt < 2; ++kt) {
            int aidx = ((cn << 6) + kt * 32 + koff) ^ ((cn & 7) << 3);
            f16x8 af = *(const f16x8*)(hbuf + aidx);
            f16x8 wf = *(const f16x8*)(ws + WSO_WC2 + ((kt << 9) + lane * 8));
            acc = MFMA(af, wf, acc);
        }
        if (cn < 10) {
            float bb = bc2[cn];
            #pragma unroll
            for (int i = 0; i < 4; ++i)
                out[(r0 + rlo + i) * 10 + cn] = acc[i] + bb;
        }
    }
}

extern "C" void kernel_launch(void* const* d_in, const int* in_sizes, int n_in,
                              void* d_out, int out_size, void* d_ws, size_t ws_size,
                              hipStream_t stream) {
    const float* x0  = (const float*)d_in[0];
    const float* tg  = (const float*)d_in[1];
    const float* W1  = (const float*)d_in[2];
    const float* b1  = (const float*)d_in[3];
    const float* W2  = (const float*)d_in[4];
    const float* b2  = (const float*)d_in[5];
    const float* Wc1 = (const float*)d_in[6];
    const float* bc1 = (const float*)d_in[7];
    const float* Wc2 = (const float*)d_in[8];
    const float* bc2 = (const float*)d_in[9];
    f16* ws = (f16*)d_ws;
    float* out = (float*)d_out;

    hipFuncSetAttribute((const void*)ode_main,
                        hipFuncAttributeMaxDynamicSharedMemorySize, SMEM_BYTES);

    pack_weights<<<(PACK_TOTAL + 255) / 256, 256, 0, stream>>>(W1, W2, Wc1, Wc2, ws);
    ode_main<<<128, 512, SMEM_BYTES, stream>>>(x0, tg, b1, b2, bc1, bc2, ws, out);
}

// Round 8
// 1630.299 us; speedup vs baseline: 1.0570x; 1.0570x over previous
//
#include <hip/hip_runtime.h>

typedef _Float16 f16;
typedef _Float16 f16x2 __attribute__((ext_vector_type(2)));
typedef _Float16 f16x8 __attribute__((ext_vector_type(8)));
typedef float f32x4 __attribute__((ext_vector_type(4)));

#define DIM 256
#define HID 512

// ws element offsets (f16 units)
#define WSO_W1  0
#define WSO_W2  131072
#define WSO_WC1 262144
#define WSO_WC2 278528
#define PACK_TOTAL 279552

// LDS byte layout (dynamic smem): W1 kt4..7 frags | yst | hbuf(+h1)
#define LDS_W1   0
#define LDS_YST  131072
#define LDS_HB   139264
#define SMEM_BYTES 155648   // 152 KB -> 1 block/CU

#define MFMA(a, b, c) __builtin_amdgcn_mfma_f32_16x16x32_f16(a, b, c, 0, 0, 0)

// Pack weights into MFMA B-fragment order (16x16x32_f16):
// frag (kt,nt): lane l, elem j -> B[k = kt*32 + (l>>4)*8 + j][n = nt*16 + (l&15)]
__global__ void pack_weights(const float* __restrict__ W1, const float* __restrict__ W2,
                             const float* __restrict__ Wc1, const float* __restrict__ Wc2,
                             f16* __restrict__ ws) {
    int gid = blockIdx.x * 256 + threadIdx.x;
    if (gid >= PACK_TOTAL) return;
    if (gid < WSO_W2) {
        int g = gid;
        int j = g & 7, lane = (g >> 3) & 63, fi = g >> 9;
        int kt = fi >> 5, nt = fi & 31;                 // 8 x 32 frags
        int k = kt * 32 + ((lane >> 4) << 3) + j;
        int n = (nt << 4) + (lane & 15);
        ws[WSO_W1 + g] = (f16)W1[k * HID + n];
    } else if (gid < WSO_WC1) {
        int g = gid - WSO_W2;
        int j = g & 7, lane = (g >> 3) & 63, fi = g >> 9;
        int kt = fi >> 4, nt = fi & 15;                 // 16 x 16 frags
        int k = kt * 32 + ((lane >> 4) << 3) + j;
        int n = (nt << 4) + (lane & 15);
        ws[WSO_W2 + g] = (f16)W2[k * DIM + n];
    } else if (gid < WSO_WC2) {
        int g = gid - WSO_WC1;
        int j = g & 7, lane = (g >> 3) & 63, fi = g >> 9;
        int kt = fi >> 2, nt = fi & 3;                  // 8 x 4 frags
        int k = kt * 32 + ((lane >> 4) << 3) + j;
        int n = (nt << 4) + (lane & 15);
        ws[WSO_WC1 + g] = (f16)Wc1[k * 64 + n];
    } else {
        int g = gid - WSO_WC2;
        int j = g & 7, lane = (g >> 3) & 63, kt = g >> 9; // 2 frags
        int k = kt * 32 + ((lane >> 4) << 3) + j;
        int n = lane & 15;
        ws[WSO_WC2 + g] = (n < 10) ? (f16)Wc2[k * 10 + n] : (f16)0.0f;
    }
}

__device__ __forceinline__ float tanh_fast(float x) {
    float e = __expf(2.0f * x);
    return 1.0f - 2.0f * __builtin_amdgcn_rcpf(e + 1.0f);
}

// f(ys) = tanh(ys@W1+b1)@W2+b2 for the block's 16 rows. 8 waves.
// Wave w: m1 n-tiles 4w..4w+3 (HID), m2 n-tiles 2w,2w+1 (DIM).
// Thread slot: row = (lane>>4)*4+i ; col = w*32 + t*16 + (lane&15), t in 0..1
// NO persistent weight registers: W1 kt4-7 from LDS, W1 kt0-3 + W2 kt0-15
// streamed from L2 each eval through small rolling windows (spill-proof).
template <class FIN, class FOUT>
__device__ __forceinline__ void feval(FIN yin, FOUT kout,
        const f16* __restrict__ ws, const f16* w1lds, f16* yst, f16* hbuf,
        int lane, int w, const float b1c[4], const float b2c[2]) {
    const int cn   = lane & 15;
    const int rlo  = (lane >> 4) << 2;
    const int koff = (lane >> 4) << 3;

#define LDW1(KT, Q) (*(const f16x8*)(ws + WSO_W1 + ((((KT) * 32 + 4 * w + (Q)) << 9) + lane * 8)))
#define LDW2(KT, T) (*(const f16x8*)(ws + WSO_W2 + ((((KT) * 16 + 2 * w + (T)) << 9) + lane * 8)))

    // ---- write stage input, swizzled f16 [16][256] ----
    #pragma unroll
    for (int t = 0; t < 2; ++t)
        #pragma unroll
        for (int i = 0; i < 4; ++i) {
            int row = rlo + i;
            int col = w * 32 + t * 16 + cn;
            int idx = ((row << 8) + col) ^ ((row & 7) << 3);
            yst[idx] = (f16)yin(t, i);
        }
    __syncthreads();   // BARRIER_A

    // ---- W1 stream window: preload kt0 (consumed after two LDS k-tiles) ----
    f16x8 w1s[4];
    #pragma unroll
    for (int q = 0; q < 4; ++q) w1s[q] = LDW1(0, q);

    // ---- m1: h = ys @ W1 ; kt order: 4,5 (LDS), 0(S), 6(L), 1(S), 7(L), 2(S), 3(S) ----
    f32x4 acc[4];
    #pragma unroll
    for (int q = 0; q < 4; ++q) acc[q] = (f32x4){0.f, 0.f, 0.f, 0.f};

#define M1_LDS(KT) { \
        int aidx = ((cn << 8) + (KT) * 32 + koff) ^ ((cn & 7) << 3); \
        f16x8 af = *(const f16x8*)(yst + aidx); \
        _Pragma("unroll") \
        for (int q = 0; q < 4; ++q) { \
            f16x8 wf = *(const f16x8*)(w1lds + ((((KT) - 4) * 32 + 4 * w + q) << 9) + lane * 8); \
            acc[q] = MFMA(af, wf, acc[q]); } }
#define M1_STR(KT, RKT, DOREF) { \
        int aidx = ((cn << 8) + (KT) * 32 + koff) ^ ((cn & 7) << 3); \
        f16x8 af = *(const f16x8*)(yst + aidx); \
        f16x8 t0 = w1s[0], t1 = w1s[1], t2 = w1s[2], t3 = w1s[3]; \
        if (DOREF) { \
            w1s[0] = LDW1(RKT, 0); w1s[1] = LDW1(RKT, 1); \
            w1s[2] = LDW1(RKT, 2); w1s[3] = LDW1(RKT, 3); } \
        acc[0] = MFMA(af, t0, acc[0]); acc[1] = MFMA(af, t1, acc[1]); \
        acc[2] = MFMA(af, t2, acc[2]); acc[3] = MFMA(af, t3, acc[3]); }

    M1_LDS(4)
    M1_LDS(5)
    M1_STR(0, 1, 1)
    M1_LDS(6)
    M1_STR(1, 2, 1)
    M1_LDS(7)
    M1_STR(2, 3, 1)
    M1_STR(3, 3, 0)
#undef M1_LDS
#undef M1_STR

    // tanh -> swizzled hbuf [16][512]
    #pragma unroll
    for (int q = 0; q < 4; ++q) {
        int hcol = ((4 * w + q) << 4) + cn;
        #pragma unroll
        for (int i = 0; i < 4; ++i) {
            float th = tanh_fast(acc[q][i] + b1c[q]);
            int row = rlo + i;
            int idx = ((row << 9) + hcol) ^ ((row & 7) << 3);
            hbuf[idx] = (f16)th;
        }
    }
    __syncthreads();   // BARRIER_B

    // ---- m2: k = h @ W2 + b2 ; all 16 kt streamed, 4-slot rolling window ----
    f16x8 w2s[4][2];
    #pragma unroll
    for (int st = 0; st < 4; ++st) {
        w2s[st][0] = LDW2(st, 0);
        w2s[st][1] = LDW2(st, 1);
    }

    f32x4 acc2[2];
    acc2[0] = (f32x4){0.f, 0.f, 0.f, 0.f};
    acc2[1] = (f32x4){0.f, 0.f, 0.f, 0.f};

#define M2(KT) { \
        int aidx = ((cn << 9) + (KT) * 32 + koff) ^ ((cn & 7) << 3); \
        f16x8 af = *(const f16x8*)(hbuf + aidx); \
        f16x8 b0 = w2s[(KT) & 3][0], b1v = w2s[(KT) & 3][1]; \
        if ((KT) < 12) { \
            w2s[(KT) & 3][0] = LDW2((KT) + 4, 0); \
            w2s[(KT) & 3][1] = LDW2((KT) + 4, 1); } \
        acc2[0] = MFMA(af, b0, acc2[0]); \
        acc2[1] = MFMA(af, b1v, acc2[1]); }

    M2(0)  M2(1)  M2(2)  M2(3)
    M2(4)  M2(5)  M2(6)  M2(7)
    M2(8)  M2(9)  M2(10) M2(11)
    M2(12) M2(13) M2(14) M2(15)
#undef M2
#undef LDW1
#undef LDW2

    #pragma unroll
    for (int t = 0; t < 2; ++t)
        #pragma unroll
        for (int i = 0; i < 4; ++i)
            kout(t, i, acc2[t][i] + b2c[t]);
}

__launch_bounds__(512)
__global__ void ode_main(const float* __restrict__ x0, const float* __restrict__ tg,
                         const float* __restrict__ b1, const float* __restrict__ b2,
                         const float* __restrict__ bc1, const float* __restrict__ bc2,
                         const f16* __restrict__ ws, float* __restrict__ out) {
    extern __shared__ char smem[];
    f16* w1lds = (f16*)(smem + LDS_W1);
    f16* yst   = (f16*)(smem + LDS_YST);
    f16* hbuf  = (f16*)(smem + LDS_HB);

    const int tid  = threadIdx.x;
    const int lane = tid & 63;
    const int w    = tid >> 6;            // wave 0..7
    const int r0   = blockIdx.x * 16;
    const int cn   = lane & 15;
    const int rlo  = (lane >> 4) << 2;

    // ---- one-time: W1 kt4..7 into LDS (frag-linear, 128 KB) ----
    #pragma unroll
    for (int u = 0; u < 16; ++u) {
        int e = (u * 512 + tid) * 8;
        *(f16x8*)(w1lds + e) = *(const f16x8*)(ws + WSO_W1 + 65536 + e);
    }

    float b1c[4], b2c[2];
    #pragma unroll
    for (int q = 0; q < 4; ++q) b1c[q] = b1[((4 * w + q) << 4) + cn];
    #pragma unroll
    for (int t = 0; t < 2; ++t) b2c[t] = b2[((2 * w + t) << 4) + cn];

    // state: row = r0 + rlo + i, col = w*32 + t*16 + cn ; y f32, k1..k5 packed f16x2
    float y[2][4];
    #pragma unroll
    for (int t = 0; t < 2; ++t)
        #pragma unroll
        for (int i = 0; i < 4; ++i)
            y[t][i] = x0[(r0 + rlo + i) * DIM + w * 32 + t * 16 + cn];

    __syncthreads();  // W1 LDS fill visible

    f16x2 k1p[2][2], k2p[2][2], k3p[2][2], k4p[2][2], k5p[2][2];
    float dt = 0.f;

#define KGET(P, t, i) ((float)P[t][(i) >> 1][(i) & 1])
#define KPUT(P, t, i, v) P[t][(i) >> 1][(i) & 1] = (f16)(v)

    for (int s = 0; s < 28; ++s) {
        if ((s & 3) == 0) { int iv = s >> 2; dt = (tg[iv + 1] - tg[iv]) * 0.25f; }

        feval([&](int t, int i) { return y[t][i]; },
              [&](int t, int i, float v) { KPUT(k1p, t, i, v); },
              ws, w1lds, yst, hbuf, lane, w, b1c, b2c);
        feval([&](int t, int i) { return y[t][i] + dt * 0.2f * KGET(k1p, t, i); },
              [&](int t, int i, float v) { KPUT(k2p, t, i, v); },
              ws, w1lds, yst, hbuf, lane, w, b1c, b2c);
        feval([&](int t, int i) { return y[t][i] + dt * (0.075f * KGET(k1p, t, i) + 0.225f * KGET(k2p, t, i)); },
              [&](int t, int i, float v) { KPUT(k3p, t, i, v); },
              ws, w1lds, yst, hbuf, lane, w, b1c, b2c);
        feval([&](int t, int i) { return y[t][i] + dt * ((44.f/45.f) * KGET(k1p, t, i) + (-56.f/15.f) * KGET(k2p, t, i)
                                                        + (32.f/9.f) * KGET(k3p, t, i)); },
              [&](int t, int i, float v) { KPUT(k4p, t, i, v); },
              ws, w1lds, yst, hbuf, lane, w, b1c, b2c);
        feval([&](int t, int i) { return y[t][i] + dt * ((19372.f/6561.f) * KGET(k1p, t, i) + (-25360.f/2187.f) * KGET(k2p, t, i)
                                                        + (64448.f/6561.f) * KGET(k3p, t, i) + (-212.f/729.f) * KGET(k4p, t, i)); },
              [&](int t, int i, float v) { KPUT(k5p, t, i, v); },
              ws, w1lds, yst, hbuf, lane, w, b1c, b2c);
        // stage 6: fold k6 straight into y (k6 never stored)
        feval([&](int t, int i) { return y[t][i] + dt * ((9017.f/3168.f) * KGET(k1p, t, i) + (-355.f/33.f) * KGET(k2p, t, i)
                                                        + (46732.f/5247.f) * KGET(k3p, t, i) + (49.f/176.f) * KGET(k4p, t, i)
                                                        + (-5103.f/18656.f) * KGET(k5p, t, i)); },
              [&](int t, int i, float v) {
                  y[t][i] += dt * ((35.f/384.f)    * KGET(k1p, t, i) + (500.f/1113.f)  * KGET(k3p, t, i)
                                 + (125.f/192.f)   * KGET(k4p, t, i) + (-2187.f/6784.f) * KGET(k5p, t, i)
                                 + (11.f/84.f)     * v);
              },
              ws, w1lds, yst, hbuf, lane, w, b1c, b2c);
    }
#undef KGET
#undef KPUT

    // ---------------- classifier head ----------------
    #pragma unroll
    for (int t = 0; t < 2; ++t)
        #pragma unroll
        for (int i = 0; i < 4; ++i) {
            int row = rlo + i;
            int col = w * 32 + t * 16 + cn;
            int idx = ((row << 8) + col) ^ ((row & 7) << 3);
            yst[idx] = (f16)y[t][i];
        }
    __syncthreads();

    // h1 = relu(y @ Wc1 + bc1): waves 0..3, one 16-col tile each; h1 in hbuf
    if (w < 4) {
        const int koff = (lane >> 4) << 3;
        f32x4 ha = (f32x4){0.f, 0.f, 0.f, 0.f};
        #pragma unroll
        for (int kt = 0; kt < 8; ++kt) {
            int aidx = ((cn << 8) + kt * 32 + koff) ^ ((cn & 7) << 3);
            f16x8 af = *(const f16x8*)(yst + aidx);
            f16x8 wf = *(const f16x8*)(ws + WSO_WC1 + (((kt * 4 + w) << 9) + lane * 8));
            ha = MFMA(af, wf, ha);
        }
        float bb = bc1[(w << 4) + cn];
        #pragma unroll
        for (int i = 0; i < 4; ++i) {
            float v = fmaxf(ha[i] + bb, 0.f);
            int row = rlo + i;
            int idx = ((row << 6) + (w << 4) + cn) ^ ((row & 7) << 3);
            hbuf[idx] = (f16)v;
        }
    }
    __syncthreads();

    // logits = h1 @ Wc2 + bc2 (packed cols 10..15 zero): wave 0
    if (w == 0) {
        const int koff = (lane >> 4) << 3;
        f32x4 acc = (f32x4){0.f, 0.f, 0.f, 0.f};
        #pragma unroll
        for (int kt = 0; kt < 2; ++kt) {
            int aidx = ((cn << 6) + kt * 32 + koff) ^ ((cn & 7) << 3);
            f16x8 af = *(const f16x8*)(hbuf + aidx);
            f16x8 wf = *(const f16x8*)(ws + WSO_WC2 + ((kt << 9) + lane * 8));
            acc = MFMA(af, wf, acc);
        }
        if (cn < 10) {
            float bb = bc2[cn];
            #pragma unroll
            for (int i = 0; i < 4; ++i)
                out[(r0 + rlo + i) * 10 + cn] = acc[i] + bb;
        }
    }
}

extern "C" void kernel_launch(void* const* d_in, const int* in_sizes, int n_in,
                              void* d_out, int out_size, void* d_ws, size_t ws_size,
                              hipStream_t stream) {
    const float* x0  = (const float*)d_in[0];
    const float* tg  = (const float*)d_in[1];
    const float* W1  = (const float*)d_in[2];
    const float* b1  = (const float*)d_in[3];
    const float* W2  = (const float*)d_in[4];
    const float* b2  = (const float*)d_in[5];
    const float* Wc1 = (const float*)d_in[6];
    const float* bc1 = (const float*)d_in[7];
    const float* Wc2 = (const float*)d_in[8];
    const float* bc2 = (const float*)d_in[9];
    f16* ws = (f16*)d_ws;
    float* out = (float*)d_out;

    hipFuncSetAttribute((const void*)ode_main,
                        hipFuncAttributeMaxDynamicSharedMemorySize, SMEM_BYTES);

    pack_weights<<<(PACK_TOTAL + 255) / 256, 256, 0, stream>>>(W1, W2, Wc1, Wc2, ws);
    ode_main<<<128, 512, SMEM_BYTES, stream>>>(x0, tg, b1, b2, bc1, bc2, ws, out);
}